// Round 1
// 396.386 us; speedup vs baseline: 1.0571x; 1.0571x over previous
//
#include <hip/hip_runtime.h>
#include <hip/hip_bf16.h>

#define NN 50000
#define EE 800000
#define GG 16
#define QD 768
#define NBUCK 196      // ceil(50000/256) dst-buckets of 256 nodes
#define EPB 4000       // edges per block in bin_edges (200 blocks)

typedef __bf16 bf16x8 __attribute__((ext_vector_type(8)));
typedef float f32x4 __attribute__((ext_vector_type(4)));

static __device__ __forceinline__ float bflo(unsigned u) {
    union { unsigned v; float f; } c; c.v = u << 16; return c.f;
}
static __device__ __forceinline__ float bfhi(unsigned u) {
    union { unsigned v; float f; } c; c.v = u & 0xffff0000u; return c.f;
}

// ---------- fused prep: convert_x + 4x prep_w5 + qkern, range-dispatched ----------
// W5T[o][k], k in [0,640): k<128 -> root[k][o]; else r=(k-128)>>7 -> W[r][(k-128)&127][o]

#define PB_CVT 6250                 // NN*128/4 / 256
#define PB_W0  (PB_CVT + 160)       // 64*640/256
#define PB_W1  (PB_W0 + 320)       // 128*640/256
#define PB_W2  (PB_W1 + 320)
#define PB_W3  (PB_W2 + 160)
#define PB_Q   (PB_W3 + 16)         // 16 graphs, one block each (K split 4-way + LDS reduce)

__global__ __launch_bounds__(256) void prep_all(
        const float* __restrict__ x, __hip_bfloat16* __restrict__ xb,
        const float* __restrict__ qe, const float* __restrict__ qn_W,
        const float* __restrict__ qn_b, float* __restrict__ q,
        const float* __restrict__ W0, const float* __restrict__ root0, __hip_bfloat16* __restrict__ W5T0,
        const float* __restrict__ W1, const float* __restrict__ root1, __hip_bfloat16* __restrict__ W5T1,
        const float* __restrict__ W2, const float* __restrict__ root2, __hip_bfloat16* __restrict__ W5T2,
        const float* __restrict__ W3, const float* __restrict__ root3, __hip_bfloat16* __restrict__ W5T3) {
    __shared__ float red[256];
    int blk = blockIdx.x, tid = threadIdx.x;
    if (blk < PB_CVT) {
        int i = blk * 256 + tid;              // float4 index
        float4 v = ((const float4*)x)[i];
        union { ushort4 u; __hip_bfloat16 h[4]; } o;
        o.h[0] = __float2bfloat16(v.x); o.h[1] = __float2bfloat16(v.y);
        o.h[2] = __float2bfloat16(v.z); o.h[3] = __float2bfloat16(v.w);
        ((ushort4*)xb)[i] = o.u;
    } else if (blk < PB_W3) {
        const float* W; const float* root; __hip_bfloat16* WT; int O, base;
        if (blk < PB_W0)      { W = W0; root = root0; WT = W5T0; O = 64;  base = PB_CVT; }
        else if (blk < PB_W1) { W = W1; root = root1; WT = W5T1; O = 128; base = PB_W0; }
        else if (blk < PB_W2) { W = W2; root = root2; WT = W5T2; O = 128; base = PB_W1; }
        else                  { W = W3; root = root3; WT = W5T3; O = 64;  base = PB_W2; }
        int idx = (blk - base) * 256 + tid;
        int o = idx / 640, k = idx - o * 640;
        float v;
        if (k < 128) v = root[(size_t)k * O + o];
        else { int r = (k - 128) >> 7, kk = (k - 128) & 127; v = W[((size_t)r * 128 + kk) * O + o]; }
        WT[idx] = __float2bfloat16(v);
    } else {
        // q projection: one block per graph; K=768 split 4 ways (chain length 192),
        // LDS reduce. Replaces the 768-long dependent-FMA tail (was ~30 us).
        int g = blk - PB_W3;
        int o = tid & 63, kc = tid >> 6;
        const float* qr = qe + (size_t)g * QD;
        float s = 0.f;
        int k0 = kc * 192;
        for (int k = k0; k < k0 + 192; ++k)
            s = fmaf(qr[k], qn_W[(size_t)k * 64 + o], s);
        red[tid] = s;
        __syncthreads();
        if (tid < 64) {
            float t = red[tid] + red[tid + 64] + red[tid + 128] + red[tid + 192] + qn_b[o];
            q[g * 64 + o] = fmaxf(t, 0.f);
        }
    }
}

// ---------- CSR build: two-level bucket sort ----------
// bucket b = dst >> 8 (256 nodes / bucket). binned entry: (src<<10)|(rel<<8)|(dst&255)

__global__ void bucket_hist(const int* __restrict__ dst, int* __restrict__ bcnt) {
    __shared__ int h[NBUCK];
    int tid = threadIdx.x;
    for (int i = tid; i < NBUCK; i += 256) h[i] = 0;
    __syncthreads();
    for (int e = blockIdx.x * 256 + tid; e < EE; e += gridDim.x * 256)
        atomicAdd(&h[dst[e] >> 8], 1);
    __syncthreads();
    for (int i = tid; i < NBUCK; i += 256) if (h[i]) atomicAdd(&bcnt[i], h[i]);
}

__global__ void bucket_scan(const int* __restrict__ bcnt, int* __restrict__ bbase,
                            int* __restrict__ bcur) {
    __shared__ int wt[4];
    int tid = threadIdx.x, lane = tid & 63, w = tid >> 6;
    int v = (tid < NBUCK) ? bcnt[tid] : 0;
    int sc = v;
#pragma unroll
    for (int off = 1; off < 64; off <<= 1) {
        int t = __shfl_up(sc, off, 64);
        if (lane >= off) sc += t;
    }
    if (lane == 63) wt[w] = sc;
    __syncthreads();
    int wbase = 0;
    for (int ww = 0; ww < w; ++ww) wbase += wt[ww];
    int excl = wbase + sc - v;
    if (tid <= NBUCK) bbase[tid] = excl;   // tid==NBUCK gets total == EE
    if (tid < NBUCK) bcur[tid] = excl;
}

// LDS-ranked binning: each block reserves contiguous runs per bucket -> dense writes
__global__ __launch_bounds__(256) void bin_edges(const int* __restrict__ src,
                                                 const int* __restrict__ dst,
                                                 const int* __restrict__ et,
                                                 int* __restrict__ bcur,
                                                 unsigned* __restrict__ binned) {
    __shared__ int lcnt[NBUCK];
    __shared__ int lbase[NBUCK];
    int tid = threadIdx.x;
    int e0 = blockIdx.x * EPB, e1 = min(e0 + EPB, EE);
    for (int base = e0; base < e1; base += 2048) {
        for (int i = tid; i < NBUCK; i += 256) lcnt[i] = 0;
        __syncthreads();
        unsigned ent[8]; int bk[8], rk[8];
#pragma unroll
        for (int k = 0; k < 8; ++k) {
            int e = base + k * 256 + tid;
            if (e < e1) {
                int d = dst[e];
                bk[k] = d >> 8;
                ent[k] = ((unsigned)src[e] << 10) | ((unsigned)et[e] << 8) | (unsigned)(d & 255);
                rk[k] = atomicAdd(&lcnt[bk[k]], 1);
            } else bk[k] = -1;
        }
        __syncthreads();
        for (int i = tid; i < NBUCK; i += 256)
            lbase[i] = lcnt[i] ? atomicAdd(&bcur[i], lcnt[i]) : 0;
        __syncthreads();
#pragma unroll
        for (int k = 0; k < 8; ++k)
            if (bk[k] >= 0) binned[lbase[bk[k]] + rk[k]] = ent[k];
        __syncthreads();
    }
}

// per-bucket fine CSR: count -> scan -> scatter in LDS; emits csr (rel-sorted per node),
// offsets, and per-(node,rel) counts cnt4
__global__ __launch_bounds__(256) void csr_fine(const int* __restrict__ bbase,
                                                const unsigned* __restrict__ binned,
                                                int* __restrict__ csr,
                                                int* __restrict__ offsets,
                                                int4* __restrict__ cnt4) {
    __shared__ int cnt[1024];   // 256 nodes x 4 rels
    __shared__ int wt[4];
    int b = blockIdx.x, tid = threadIdx.x, lane = tid & 63, w = tid >> 6;
    int seg0 = bbase[b], seg1 = bbase[b + 1];
    for (int i = tid; i < 1024; i += 256) cnt[i] = 0;
    __syncthreads();
    for (int e = seg0 + tid; e < seg1; e += 256) {
        unsigned u = binned[e];
        atomicAdd(&cnt[(u & 255) * 4 + ((u >> 8) & 3)], 1);
    }
    __syncthreads();
    int c0 = cnt[tid * 4], c1 = cnt[tid * 4 + 1], c2 = cnt[tid * 4 + 2], c3 = cnt[tid * 4 + 3];
    int s = c0 + c1 + c2 + c3;
    int sc = s;
#pragma unroll
    for (int off = 1; off < 64; off <<= 1) {
        int t = __shfl_up(sc, off, 64);
        if (lane >= off) sc += t;
    }
    if (lane == 63) wt[w] = sc;
    __syncthreads();
    int wbase = 0;
    for (int ww = 0; ww < w; ++ww) wbase += wt[ww];
    int excl = wbase + sc - s;
    cnt[tid * 4]     = excl;
    cnt[tid * 4 + 1] = excl + c0;
    cnt[tid * 4 + 2] = excl + c0 + c1;
    cnt[tid * 4 + 3] = excl + c0 + c1 + c2;
    int node = b * 256 + tid;
    if (node < NN) {
        offsets[node] = seg0 + excl;
        cnt4[node] = make_int4(c0, c1, c2, c3);
    }
    if (b == NBUCK - 1 && tid == 0) offsets[NN] = EE;
    __syncthreads();
    for (int e = seg0 + tid; e < seg1; e += 256) {
        unsigned u = binned[e];
        int r = atomicAdd(&cnt[(u & 255) * 4 + ((u >> 8) & 3)], 1);
        csr[seg0 + r] = (int)(((u >> 10) << 2) | ((u >> 8) & 3));   // (src<<2)|rel
    }
}

// ---------- agg_x: segment-lockstep gather, PROVABLY wave-uniform scalar path ----------
// X5agg[node] = [ mean_r0 (128) | mean_r1 | mean_r2 | mean_r3 ]  bf16 (512 cols)
// One wave per node. node is pinned to an SGPR via readfirstlane so that
// offsets/cnt4 become s_load, the csr entry itself becomes a scalar load
// (fully uniform address -> no pk vector load, no v_readlane), the zero-page
// base select becomes s_cselect_b64, and the gather is global_load_dword with
// SGPR base + loop-invariant lane*4 offset. Per-slot VALU = 4 (bf16 unpack+acc).

__global__ __launch_bounds__(256) void agg_x(const __hip_bfloat16* __restrict__ X,
                                             const int* __restrict__ offsets,
                                             const int4* __restrict__ cnt4,
                                             const int* __restrict__ csr,
                                             const float* __restrict__ zpage,
                                             __hip_bfloat16* __restrict__ X5agg) {
    int lane = threadIdx.x & 63;
    int node = __builtin_amdgcn_readfirstlane(blockIdx.x * 4 + (threadIdx.x >> 6));
    const char* xb = (const char*)X;
    const char* zp = (const char*)zpage;
    int e0 = offsets[node];          // uniform -> s_load
    int4 c4 = cnt4[node];            // uniform -> s_load_dwordx4
    int st[4];
    st[0] = 0; st[1] = c4.x; st[2] = st[1] + c4.y; st[3] = st[2] + c4.z;
    int cs[4] = {c4.x, c4.y, c4.z, c4.w};
    int maxc = max(max(cs[0], cs[1]), max(cs[2], cs[3]));
    float aL[4] = {0.f, 0.f, 0.f, 0.f}, aH[4] = {0.f, 0.f, 0.f, 0.f};
    for (int i = 0; i < maxc; i += 2) {
        const char* bp[8];
#pragma unroll
        for (int jj = 0; jj < 2; ++jj) {
            int i2 = i + jj;                       // uniform
#pragma unroll
            for (int r = 0; r < 4; ++r) {
                int p = csr[min(e0 + st[r] + i2, EE - 1)];        // uniform -> s_load
                bp[jj * 4 + r] = (i2 < cs[r]) ? xb + (size_t)(p >> 2) * 256 : zp;  // s_cselect
            }
        }
        unsigned u[8];
#pragma unroll
        for (int k = 0; k < 8; ++k)
            u[k] = *(const unsigned*)(bp[k] + lane * 4);          // saddr + v lane*4
#pragma unroll
        for (int k = 0; k < 8; ++k) {
            int r = k & 3;
            aL[r] += bflo(u[k]);
            aH[r] += bfhi(u[k]);
        }
    }
    char* x5 = (char*)X5agg;
#pragma unroll
    for (int r = 0; r < 4; ++r) {
        float iv = 1.f / fmaxf((float)cs[r], 1.f);
        __hip_bfloat16 g0 = __float2bfloat16(aL[r] * iv);
        __hip_bfloat16 g1 = __float2bfloat16(aH[r] * iv);
        ushort2 pkd;
        pkd.x = *(unsigned short*)&g0; pkd.y = *(unsigned short*)&g1;
        *(ushort2*)(x5 + (size_t)node * 1024 + r * 256 + lane * 4) = pkd;
    }
}

// ---------- dense5: out[N][O] = [Xself | X5agg] @ W5T^T + bias, fused epilogue ----------
// MODE 0: O=64, relu, write bf16 [h | q[batch]] (128 cols). MODE 1: O=128, relu bf16.
// MODE 2: O=64, no relu, fp32 to out.

template <int O, int MODE>
__global__ __launch_bounds__(256) void dense5(const __hip_bfloat16* __restrict__ Xself,
                                              const __hip_bfloat16* __restrict__ X5agg,
                                              const __hip_bfloat16* __restrict__ W5T,
                                              const float* __restrict__ bias,
                                              const float* __restrict__ q,
                                              const int* __restrict__ batch,
                                              __hip_bfloat16* __restrict__ xnext,
                                              float* __restrict__ out) {
    __shared__ char lds[16384];
    constexpr int NCT = O / 16;
    int tid = threadIdx.x;
    int wave = tid >> 6, lane = tid & 63;
    int quad = lane >> 4, l15 = lane & 15;
    int mbase = blockIdx.x * 128 + wave * 32;
    const __bf16* Ws = (const __bf16*)W5T;

    f32x4 acc[2][NCT];
#pragma unroll
    for (int mt = 0; mt < 2; ++mt)
#pragma unroll
        for (int t = 0; t < NCT; ++t) acc[mt][t] = f32x4{0, 0, 0, 0};

    int arow0 = min(mbase + l15, NN - 1);
    int arow1 = min(mbase + 16 + l15, NN - 1);
    const __bf16* aps0 = (const __bf16*)Xself + (size_t)arow0 * 128;
    const __bf16* aps1 = (const __bf16*)Xself + (size_t)arow1 * 128;
    const __bf16* apg0 = (const __bf16*)X5agg + (size_t)arow0 * 512;
    const __bf16* apg1 = (const __bf16*)X5agg + (size_t)arow1 * 512;

    for (int kc = 0; kc < 10; ++kc) {
        int k0 = kc * 64;
        const __bf16* a0base = (kc < 2) ? aps0 + kc * 64 : apg0 + (kc - 2) * 64;
        const __bf16* a1base = (kc < 2) ? aps1 + kc * 64 : apg1 + (kc - 2) * 64;
        __syncthreads();
        constexpr int NF = NCT * 2 * 64;     // fragments per chunk (512 / 1024)
#pragma unroll
        for (int i = 0; i < NF / 256; ++i) {
            int f = tid + i * 256;
            int fl = f & 63;
            int o = (f >> 7) * 16 + (fl & 15);
            int kk = k0 + ((f >> 6) & 1) * 32 + ((fl >> 4) & 3) * 8;
            *(uint4*)(lds + f * 16) = *(const uint4*)(Ws + (size_t)o * 640 + kk);
        }
        __syncthreads();
#pragma unroll
        for (int ks = 0; ks < 2; ++ks) {
            bf16x8 a0 = *(const bf16x8*)(a0base + ks * 32 + quad * 8);
            bf16x8 a1 = *(const bf16x8*)(a1base + ks * 32 + quad * 8);
#pragma unroll
            for (int t = 0; t < NCT; ++t) {
                bf16x8 b = *(const bf16x8*)(lds + ((t * 2 + ks) * 64 + lane) * 16);
                acc[0][t] = __builtin_amdgcn_mfma_f32_16x16x32_bf16(a0, b, acc[0][t], 0, 0, 0);
                acc[1][t] = __builtin_amdgcn_mfma_f32_16x16x32_bf16(a1, b, acc[1][t], 0, 0, 0);
            }
        }
    }
    __syncthreads();

    if (MODE == 2) {
#pragma unroll
        for (int mt = 0; mt < 2; ++mt)
#pragma unroll
            for (int t = 0; t < NCT; ++t) {
                int col = t * 16 + l15;
                float bv = bias[col];
#pragma unroll
                for (int reg = 0; reg < 4; ++reg) {
                    int row = mbase + mt * 16 + quad * 4 + reg;
                    if (row < NN) out[(size_t)row * 64 + col] = acc[mt][t][reg] + bv;
                }
            }
        return;
    }

    // bf16 path: per-wave LDS tile [16][128], one row-tile at a time
    __hip_bfloat16* tp = (__hip_bfloat16*)(lds + wave * 4096);
#pragma unroll
    for (int mt = 0; mt < 2; ++mt) {
        int m0 = mbase + mt * 16;
#pragma unroll
        for (int t = 0; t < NCT; ++t) {
            int col = t * 16 + l15;
            float bv = bias[col];
#pragma unroll
            for (int reg = 0; reg < 4; ++reg)
                tp[(quad * 4 + reg) * 128 + col] =
                    __float2bfloat16(fmaxf(acc[mt][t][reg] + bv, 0.f));
        }
        if (MODE == 0) {
            // fill q columns 64..127: lane -> row=lane>>2, colseg=(lane&3)*16
            int row = lane >> 2;
            int cs = (lane & 3) * 16;
            int rnode = min(m0 + row, NN - 1);
            int g = batch[rnode];
#pragma unroll
            for (int i = 0; i < 4; ++i) {
                float4 v = *(const float4*)(q + g * 64 + cs + i * 4);
                __hip_bfloat16 q0 = __float2bfloat16(v.x), q1 = __float2bfloat16(v.y);
                __hip_bfloat16 q2 = __float2bfloat16(v.z), q3 = __float2bfloat16(v.w);
                ushort4 pk;
                pk.x = *(unsigned short*)&q0; pk.y = *(unsigned short*)&q1;
                pk.z = *(unsigned short*)&q2; pk.w = *(unsigned short*)&q3;
                *(ushort4*)(tp + row * 128 + 64 + cs + i * 4) = pk;
            }
        }
        // store 16 rows x 256 B, 16B/lane coalesced
#pragma unroll
        for (int p = 0; p < 4; ++p) {
            int c = p * 64 + lane;
            int row = m0 + (c >> 4);
            if (row < NN)
                *(uint4*)((char*)xnext + (size_t)row * 256 + (c & 15) * 16) =
                    *(const uint4*)((const char*)tp + c * 16);
        }
    }
}

// ---------- launch ----------

static inline size_t rup(size_t x) { return (x + 255) & ~(size_t)255; }

extern "C" void kernel_launch(void* const* d_in, const int* in_sizes, int n_in,
                              void* d_out, int out_size, void* d_ws, size_t ws_size,
                              hipStream_t stream) {
    const float* x      = (const float*)d_in[0];
    const int*   esrc   = (const int*)d_in[1];
    const int*   edst   = esrc + EE;
    const int*   eattr  = (const int*)d_in[2];
    const int*   batch  = (const int*)d_in[3];
    const float* qe     = (const float*)d_in[4];
    const float* qn_W   = (const float*)d_in[5];
    const float* qn_b   = (const float*)d_in[6];
    const float* W0 = (const float*)d_in[7],  *root0 = (const float*)d_in[8],  *b0 = (const float*)d_in[9];
    const float* W1 = (const float*)d_in[10], *root1 = (const float*)d_in[11], *b1 = (const float*)d_in[12];
    const float* W2 = (const float*)d_in[13], *root2 = (const float*)d_in[14], *b2 = (const float*)d_in[15];
    const float* W3 = (const float*)d_in[16], *root3 = (const float*)d_in[17], *b3 = (const float*)d_in[18];
    float* out = (float*)d_out;

    char* w = (char*)d_ws;
    float* q       = (float*)w;  w += rup(GG * 64 * 4);
    float* zpage   = (float*)w;  w += rup(256);
    int*   offsets = (int*)w;    w += rup(((size_t)NN + 1) * 4);
    int4*  cnt4    = (int4*)w;   w += rup((size_t)NN * 16);
    int*   bcnt    = (int*)w;    w += rup((size_t)NBUCK * 4);
    int*   bbase   = (int*)w;    w += rup(((size_t)NBUCK + 1) * 4);
    int*   bcur    = (int*)w;    w += rup((size_t)NBUCK * 4);
    unsigned* binned = (unsigned*)w; w += rup((size_t)EE * 4);
    int*   csr     = (int*)w;    w += rup((size_t)EE * 4);
    __hip_bfloat16* W5T0 = (__hip_bfloat16*)w; w += rup((size_t)64 * 640 * 2);
    __hip_bfloat16* W5T1 = (__hip_bfloat16*)w; w += rup((size_t)128 * 640 * 2);
    __hip_bfloat16* W5T2 = (__hip_bfloat16*)w; w += rup((size_t)128 * 640 * 2);
    __hip_bfloat16* W5T3 = (__hip_bfloat16*)w; w += rup((size_t)64 * 640 * 2);
    __hip_bfloat16* xb0 = (__hip_bfloat16*)w;  w += rup((size_t)NN * 128 * 2);
    __hip_bfloat16* xb1 = (__hip_bfloat16*)w;  w += rup((size_t)NN * 128 * 2);
    __hip_bfloat16* X5  = (__hip_bfloat16*)w;  w += rup((size_t)NN * 512 * 2);

    hipMemsetAsync(bcnt, 0, (size_t)NBUCK * 4, stream);
    hipMemsetAsync(zpage, 0, 256, stream);   // zero page for masked gathers

    // fused prep: input conversion + weight transposes + question projection
    prep_all<<<PB_Q, 256, 0, stream>>>(x, xb0, qe, qn_W, qn_b, q,
                                       W0, root0, W5T0, W1, root1, W5T1,
                                       W2, root2, W5T2, W3, root3, W5T3);

    // CSR build: bucket sort
    bucket_hist<<<256, 256, 0, stream>>>(edst, bcnt);
    bucket_scan<<<1, 256, 0, stream>>>(bcnt, bbase, bcur);
    bin_edges<<<(EE + EPB - 1) / EPB, 256, 0, stream>>>(esrc, edst, eattr, bcur, binned);
    csr_fine<<<NBUCK, 256, 0, stream>>>(bbase, binned, csr, offsets, cnt4);

    int aggblk = NN / 4;                   // 12500
    int dblk = (NN + 127) / 128;           // 391

    // layer 0: xb0 -> X5 -> [h|q] xb1
    agg_x<<<aggblk, 256, 0, stream>>>(xb0, offsets, cnt4, csr, zpage, X5);
    dense5<64, 0><<<dblk, 256, 0, stream>>>(xb0, X5, W5T0, b0, q, batch, xb1, nullptr);

    // layer 1: xb1 -> X5 -> xb0
    agg_x<<<aggblk, 256, 0, stream>>>(xb1, offsets, cnt4, csr, zpage, X5);
    dense5<128, 1><<<dblk, 256, 0, stream>>>(xb1, X5, W5T1, b1, nullptr, nullptr, xb0, nullptr);

    // layer 2: xb0 -> X5 -> xb1
    agg_x<<<aggblk, 256, 0, stream>>>(xb0, offsets, cnt4, csr, zpage, X5);
    dense5<128, 1><<<dblk, 256, 0, stream>>>(xb0, X5, W5T2, b2, nullptr, nullptr, xb1, nullptr);

    // layer 3: xb1 -> X5 -> fp32 out
    agg_x<<<aggblk, 256, 0, stream>>>(xb1, offsets, cnt4, csr, zpage, X5);
    dense5<64, 2><<<dblk, 256, 0, stream>>>(xb1, X5, W5T3, b3, nullptr, nullptr, nullptr, out);
}